// Round 19
// baseline (399.277 us; speedup 1.0000x reference)
//
#include <hip/hip_runtime.h>
#include <hip/hip_bf16.h>
#include <math.h>

// ---------------- problem constants ----------------
static constexpr int CB     = 32;
static constexpr int CH     = 56;
static constexpr int CW     = 56;
static constexpr int CC     = 192;
static constexpr int CSHIFT = 3;
static constexpr int CN     = 49;
static constexpr int CNW    = 64;
static constexpr int CL     = CH * CW;            // 3136
static constexpr int CM     = CB * CNW * CN;      // 100352
static constexpr int CHID   = 768;
static constexpr int LN1_BLOCKS  = CM / 4;                    // 25088
static constexpr int PREP_TOTAL  = 110592 + 36864 + 147456 + 147456 + 98304;
static constexpr int PREP_BLOCKS = (PREP_TOTAL + 255) / 256;  // 2112

typedef __attribute__((ext_vector_type(8))) __bf16 bf16x8;
typedef __attribute__((ext_vector_type(4))) float  f32x4;

__device__ __forceinline__ float bfu2f(unsigned short u) {
  union { unsigned i; float f; } c; c.i = (unsigned)u << 16; return c.f;
}
__device__ __forceinline__ unsigned short f2bu(float f) {
  __hip_bfloat16 b = __float2bfloat16(f);
  return *(unsigned short*)&b;
}
// sigmoid-form GELU: x*sigmoid(1.702x)
__device__ __forceinline__ float gelu_fast(float v) {
  float e = __expf(-1.702f * v);
  return __fdividef(v, 1.0f + e);
}

#define GLOAD16(g, l) __builtin_amdgcn_global_load_lds( \
    (__attribute__((address_space(1))) void*)(g),       \
    (__attribute__((address_space(3))) void*)(l), 16, 0, 0)

// ---------------- fused LN1(+roll+window) AND one-shot prep (weights + bias2) ----------------
__global__ __launch_bounds__(256)
void ln1_prep_kernel(const float* __restrict__ xin, const float* __restrict__ gamma,
                     const float* __restrict__ beta, __hip_bfloat16* __restrict__ out,
                     const float* __restrict__ qkv_w, const float* __restrict__ proj_w,
                     const float* __restrict__ fc1_w, const float* __restrict__ fc2_w,
                     const float* __restrict__ btab,
                     __hip_bfloat16* __restrict__ wq, __hip_bfloat16* __restrict__ wp,
                     __hip_bfloat16* __restrict__ w1, __hip_bfloat16* __restrict__ w2,
                     float* __restrict__ bias2)
{
  if (blockIdx.x < LN1_BLOCKS) {
    const int wid = threadIdx.x >> 6, lane = threadIdx.x & 63;
    const int m = blockIdx.x * 4 + wid;
    int b   = m / (CNW * CN);
    int rem = m - b * (CNW * CN);
    int nw  = rem / CN, t = rem - nw * CN;
    int wr = nw >> 3, wc = nw & 7;
    int ti = t / 7, tj = t - ti * 7;
    int sr = wr * 7 + ti + CSHIFT; if (sr >= CH) sr -= CH;
    int sc = wc * 7 + tj + CSHIFT; if (sc >= CW) sc -= CW;
    size_t src = ((size_t)b * CL + (size_t)sr * CW + sc) * CC;
    float v0 = xin[src + lane], v1 = xin[src + lane + 64], v2 = xin[src + lane + 128];
    float s  = v0 + v1 + v2;
    float sq = v0 * v0 + v1 * v1 + v2 * v2;
    #pragma unroll
    for (int off = 32; off; off >>= 1) { s += __shfl_xor(s, off); sq += __shfl_xor(sq, off); }
    const float mu  = s * (1.0f / CC);
    const float inv = rsqrtf(sq * (1.0f / CC) - mu * mu + 1e-5f);
    const size_t dst = (size_t)m * CC;
    out[dst + lane      ] = __float2bfloat16((v0 - mu) * inv * gamma[lane      ] + beta[lane      ]);
    out[dst + lane + 64 ] = __float2bfloat16((v1 - mu) * inv * gamma[lane + 64 ] + beta[lane + 64 ]);
    out[dst + lane + 128] = __float2bfloat16((v2 - mu) * inv * gamma[lane + 128] + beta[lane + 128]);
    return;
  }

  int idx = (blockIdx.x - LN1_BLOCKS) * 256 + threadIdx.x;
  if (idx < 110592) {                       // wq: [192][576] -> [576][192]
    int k = idx / 576, n = idx - k * 576;
    wq[n * 192 + k] = __float2bfloat16(qkv_w[idx]);
    return;
  }
  idx -= 110592;
  if (idx < 36864) {                        // wp: [192][192]
    int k = idx / 192, n = idx - k * 192;
    wp[n * 192 + k] = __float2bfloat16(proj_w[idx]);
    return;
  }
  idx -= 36864;
  if (idx < 147456) {                       // w1: [192][768] -> [768][192]
    int k = idx / 768, n = idx - k * 768;
    w1[n * 192 + k] = __float2bfloat16(fc1_w[idx]);
    return;
  }
  idx -= 147456;
  if (idx < 147456) {                       // w2: [768][192] -> [192][768]
    int k = idx / 192, n = idx - k * 192;
    w2[n * 768 + k] = __float2bfloat16(fc2_w[idx]);
    return;
  }
  idx -= 147456;
  if (idx < 98304) {                        // bias2: [4][6][64][64]
    int j = idx & 63, i = (idx >> 6) & 63;
    int rest = idx >> 12;
    int h = rest % 6, wt = rest / 6;
    float val;
    if (i >= 49 || j >= 49) {
      val = -INFINITY;
    } else {
      int ti = i / 7, ci = i - ti * 7;
      int tj = j / 7, cj = j - tj * 7;
      val = btab[((ti - tj + 6) * 13 + (ci - cj + 6)) * 6 + h];
      int hri = (wt & 2) ? ((ti < 4) ? 1 : 2) : 0;
      int hci = (wt & 1) ? ((ci < 4) ? 1 : 2) : 0;
      int hrj = (wt & 2) ? ((tj < 4) ? 1 : 2) : 0;
      int hcj = (wt & 1) ? ((cj < 4) ? 1 : 2) : 0;
      if (hri * 3 + hci != hrj * 3 + hcj) val -= 100.0f;
    }
    bias2[idx] = val;
  }
}

// ---------------- LN2 (bf16 in/out, no roll) ----------------
__global__ __launch_bounds__(256)
void ln_kernel(const __hip_bfloat16* __restrict__ xin, const float* __restrict__ gamma,
               const float* __restrict__ beta, __hip_bfloat16* __restrict__ out)
{
  const int wid = threadIdx.x >> 6, lane = threadIdx.x & 63;
  const int m = blockIdx.x * 4 + wid;
  const size_t src = (size_t)m * CC;
  const unsigned short* xb = (const unsigned short*)xin;
  float v0 = bfu2f(xb[src + lane      ]);
  float v1 = bfu2f(xb[src + lane + 64 ]);
  float v2 = bfu2f(xb[src + lane + 128]);
  float s  = v0 + v1 + v2;
  float sq = v0 * v0 + v1 * v1 + v2 * v2;
  #pragma unroll
  for (int off = 32; off; off >>= 1) { s += __shfl_xor(s, off); sq += __shfl_xor(sq, off); }
  const float mu  = s * (1.0f / CC);
  const float inv = rsqrtf(sq * (1.0f / CC) - mu * mu + 1e-5f);
  out[src + lane      ] = __float2bfloat16((v0 - mu) * inv * gamma[lane      ] + beta[lane      ]);
  out[src + lane + 64 ] = __float2bfloat16((v1 - mu) * inv * gamma[lane + 64 ] + beta[lane + 64 ]);
  out[src + lane + 128] = __float2bfloat16((v2 - mu) * inv * gamma[lane + 128] + beta[lane + 128]);
}

// ---------------- MFMA bf16 GEMM (round-11 skeleton) ----------------
// MODE 2: gelu bf16 (fc1) | 4: scatter bf16 resid (proj) | 5: bf16-resid f32 out (fc2)
template<int K, int N, int BN, int MODE>
__global__ __launch_bounds__(256)
void gemm_mfma(const __hip_bfloat16* __restrict__ Ain, const __hip_bfloat16* __restrict__ Wt,
               const float* __restrict__ bias, void* __restrict__ Outv,
               const void* __restrict__ residv)
{
  constexpr int NT = BN / 32;
  __shared__ short As[128 * 64];
  __shared__ short Bs[BN * 64];

  const int tid  = threadIdx.x;
  const int lane = tid & 63, wid = tid >> 6;

  const int nbx = N / BN;
  const int nwg = nbx * gridDim.y;
  const int wg  = blockIdx.y * nbx + blockIdx.x;
  const int swz = (wg & 7) * (nwg >> 3) + (wg >> 3);
  const int row0 = (swz / nbx) * 128, col0 = (swz % nbx) * BN;

  const int wm = wid >> 1, wn = wid & 1;
  const int lr = lane & 15, lg = lane >> 4;

  const short* A  = (const short*)Ain;
  const short* W  = (const short*)Wt;

  f32x4 acc[4][NT] = {};

  #pragma unroll
  for (int kk = 0; kk < K; kk += 64) {
    #pragma unroll
    for (int it = 0; it < 4; ++it) {
      int c = it * 256 + tid;
      int row = c >> 3, slot = c & 7;
      int kg = (slot ^ (row & 7)) * 8;
      GLOAD16(A + (size_t)(row0 + row) * K + kk + kg, As + c * 8);
    }
    #pragma unroll
    for (int it = 0; it < BN / 32; ++it) {
      int c = it * 256 + tid;
      int row = c >> 3, slot = c & 7;
      int kg = (slot ^ (row & 7)) * 8;
      GLOAD16(W + (size_t)(col0 + row) * K + kk + kg, Bs + c * 8);
    }
    __syncthreads();

    #pragma unroll
    for (int kh = 0; kh < 2; ++kh) {
      const int sb = kh * 4 + lg;
      bf16x8 bfr[NT];
      #pragma unroll
      for (int nt = 0; nt < NT; ++nt) {
        int br = wn * (BN / 2) + nt * 16 + lr;
        bfr[nt] = *(const bf16x8*)(Bs + br * 64 + (sb ^ (br & 7)) * 8);
      }
      #pragma unroll
      for (int m = 0; m < 4; ++m) {
        int ar = wm * 64 + m * 16 + lr;
        bf16x8 afr = *(const bf16x8*)(As + ar * 64 + (sb ^ (ar & 7)) * 8);
        #pragma unroll
        for (int nt = 0; nt < NT; ++nt)
          acc[m][nt] = __builtin_amdgcn_mfma_f32_16x16x32_bf16(afr, bfr[nt], acc[m][nt], 0, 0, 0);
      }
    }
    __syncthreads();
  }

  const int colA = col0 + wn * (BN / 2) + lr;
  float bv[NT];
  #pragma unroll
  for (int nt = 0; nt < NT; ++nt) bv[nt] = bias[colA + nt * 16];

  #pragma unroll
  for (int m = 0; m < 4; ++m) {
    #pragma unroll
    for (int r = 0; r < 4; ++r) {
      const int mrow = row0 + wm * 64 + m * 16 + lg * 4 + r;
      if (MODE == 4) {
        int b = mrow / (CNW * CN);
        int rem = mrow - b * (CNW * CN);
        int nw = rem / CN, t = rem - nw * CN;
        int wr = nw >> 3, wc = nw & 7;
        int ti = t / 7, tj = t - ti * 7;
        int dr = wr * 7 + ti + CSHIFT; if (dr >= CH) dr -= CH;
        int dc = wc * 7 + tj + CSHIFT; if (dc >= CW) dc -= CW;
        const size_t dst = ((size_t)b * CL + (size_t)dr * CW + dc) * CC + colA;
        const float* resid = (const float*)residv;
        __hip_bfloat16* O = (__hip_bfloat16*)Outv;
        #pragma unroll
        for (int nt = 0; nt < NT; ++nt)
          O[dst + nt * 16] = __float2bfloat16(resid[dst + nt * 16] + acc[m][nt][r] + bv[nt]);
      } else if (MODE == 2) {
        __hip_bfloat16* O = (__hip_bfloat16*)Outv;
        const size_t rr = (size_t)mrow * N + colA;
        #pragma unroll
        for (int nt = 0; nt < NT; ++nt)
          O[rr + nt * 16] = __float2bfloat16(gelu_fast(acc[m][nt][r] + bv[nt]));
      } else {
        float* O = (float*)Outv;
        const unsigned short* resid = (const unsigned short*)residv;
        const size_t rr = (size_t)mrow * N + colA;
        #pragma unroll
        for (int nt = 0; nt < NT; ++nt)
          O[rr + nt * 16] = bfu2f(resid[rr + nt * 16]) + acc[m][nt][r] + bv[nt];
      }
    }
  }
}

// ---------------- fused qkv + windowed attention ----------------
// Block = 1 window (384 thr, 6 waves); wave = head. Each wave computes Q,K,V by MFMA
// (A = xw window rows from global, L1/L2-hot; B = wq cols from L2), stores Q,K to
// per-wave LDS [64][36] (bank-free), V^T to [32][72] aliasing Q after qf is in regs.
// Then S^T/softmax/P-shuffle/PV verbatim from the validated round-16 kernel.
// No __syncthreads: all LDS is wave-private.
__global__ __launch_bounds__(384)
void attn_fused_kernel(const unsigned short* __restrict__ xw,
                       const unsigned short* __restrict__ wq,   // [576][192] bf16
                       const float* __restrict__ qkv_b,
                       const float* __restrict__ bias2,
                       __hip_bfloat16* __restrict__ attnout)
{
  __shared__ unsigned short QK[6][2][2304];   // [wave][q|k][64*36]; V^T (32*72) aliases [..][0]

  const int wid = threadIdx.x >> 6, lane = threadIdx.x & 63;
  const int w = blockIdx.x, h = wid;
  const int lr = lane & 15, lg = lane >> 4;
  const int nw = w & 63;
  const int wt = (((nw >> 3) == 7) ? 2 : 0) + (((nw & 7) == 7) ? 1 : 0);
  const unsigned short* xg = xw + (size_t)w * 49 * 192;
  unsigned short* q_s = QK[wid][0];
  unsigned short* k_s = QK[wid][1];
  unsigned short* vt  = QK[wid][0];           // alias (Q dead once qf is in regs)
  const float scale = 0.17677669529663687f;

  // ---- Q and K passes: C[tok][d] = xw @ wq_slice ----
  #pragma unroll
  for (int op = 0; op < 2; ++op) {
    f32x4 a4[4][2] = {};
    #pragma unroll
    for (int ksl = 0; ksl < 6; ++ksl) {
      bf16x8 bfr[2];
      #pragma unroll
      for (int nt = 0; nt < 2; ++nt)
        bfr[nt] = *(const bf16x8*)(wq + (size_t)(op * 192 + h * 32 + nt * 16 + lr) * 192 + ksl * 32 + lg * 8);
      #pragma unroll
      for (int it = 0; it < 4; ++it) {
        int tok = it * 16 + lr; if (tok > 48) tok = 48;
        bf16x8 af = *(const bf16x8*)(xg + (size_t)tok * 192 + ksl * 32 + lg * 8);
        a4[it][0] = __builtin_amdgcn_mfma_f32_16x16x32_bf16(af, bfr[0], a4[it][0], 0, 0, 0);
        a4[it][1] = __builtin_amdgcn_mfma_f32_16x16x32_bf16(af, bfr[1], a4[it][1], 0, 0, 0);
      }
    }
    unsigned short* dst = op ? k_s : q_s;
    #pragma unroll
    for (int nt = 0; nt < 2; ++nt) {
      const float bb = qkv_b[op * 192 + h * 32 + nt * 16 + lr];
      #pragma unroll
      for (int it = 0; it < 4; ++it)
        #pragma unroll
        for (int r = 0; r < 4; ++r)
          dst[(it * 16 + lg * 4 + r) * 36 + nt * 16 + lr] = f2bu(a4[it][nt][r] + bb);
    }
  }

  // ---- operand fragments from LDS ----
  bf16x8 qf[4], kf[4];
  #pragma unroll
  for (int it = 0; it < 4; ++it)
    qf[it] = *(const bf16x8*)&q_s[(it * 16 + lr) * 36 + lg * 8];
  #pragma unroll
  for (int jt = 0; jt < 4; ++jt)
    kf[jt] = *(const bf16x8*)&k_s[(jt * 16 + lr) * 36 + lg * 8];

  // ---- S^T = K @ Q^T ----
  f32x4 accs[4][4] = {};
  __builtin_amdgcn_s_setprio(1);
  #pragma unroll
  for (int jt = 0; jt < 4; ++jt)
    #pragma unroll
    for (int it = 0; it < 4; ++it)
      accs[jt][it] = __builtin_amdgcn_mfma_f32_16x16x32_bf16(kf[jt], qf[it], accs[jt][it], 0, 0, 0);
  __builtin_amdgcn_s_setprio(0);

  // ---- V pass -> V^T in LDS (overwrites q_s; qf already consumed) ----
  {
    f32x4 a4[4][2] = {};
    #pragma unroll
    for (int ksl = 0; ksl < 6; ++ksl) {
      bf16x8 bfr[2];
      #pragma unroll
      for (int nt = 0; nt < 2; ++nt)
        bfr[nt] = *(const bf16x8*)(wq + (size_t)(384 + h * 32 + nt * 16 + lr) * 192 + ksl * 32 + lg * 8);
      #pragma unroll
      for (int it = 0; it < 4; ++it) {
        int tok = it * 16 + lr; if (tok > 48) tok = 48;
        bf16x8 af = *(const bf16x8*)(xg + (size_t)tok * 192 + ksl * 32 + lg * 8);
        a4[it][0] = __builtin_amdgcn_mfma_f32_16x16x32_bf16(af, bfr[0], a4[it][0], 0, 0, 0);
        a4[it][1] = __builtin_amdgcn_mfma_f32_16x16x32_bf16(af, bfr[1], a4[it][1], 0, 0, 0);
      }
    }
    #pragma unroll
    for (int nt = 0; nt < 2; ++nt) {
      const float bb = qkv_b[384 + h * 32 + nt * 16 + lr];
      #pragma unroll
      for (int it = 0; it < 4; ++it)
        #pragma unroll
        for (int r = 0; r < 4; ++r)
          vt[(nt * 16 + lr) * 72 + it * 16 + lg * 4 + r] = f2bu(a4[it][nt][r] + bb);
    }
  }

  // ---- V^T B-fragments ----
  bf16x8 vb[2][2];
  #pragma unroll
  for (int ks = 0; ks < 2; ++ks)
    #pragma unroll
    for (int nt = 0; nt < 2; ++nt)
      vb[ks][nt] = *(const bf16x8*)&vt[(nt * 16 + lr) * 72 + ks * 32 + lg * 8];

  const float* brow = bias2 + ((size_t)(wt * 6 + h) * 64) * 64;
  const int src0 = lr + ((lg & 1) << 5);
  f32x4 o[4][2] = {};

  #pragma unroll
  for (int it = 0; it < 4; ++it) {
    const int i = it * 16 + lr;
    float s[4][4];
    #pragma unroll
    for (int jt = 0; jt < 4; ++jt) {
      float4 bv = *(const float4*)(brow + (size_t)i * 64 + jt * 16 + lg * 4);
      s[jt][0] = fmaf(accs[jt][it][0], scale, bv.x);
      s[jt][1] = fmaf(accs[jt][it][1], scale, bv.y);
      s[jt][2] = fmaf(accs[jt][it][2], scale, bv.z);
      s[jt][3] = fmaf(accs[jt][it][3], scale, bv.w);
    }
    float mx = s[0][0];
    #pragma unroll
    for (int jt = 0; jt < 4; ++jt)
      #pragma unroll
      for (int r = 0; r < 4; ++r) mx = fmaxf(mx, s[jt][r]);
    mx = fmaxf(mx, __shfl_xor(mx, 16));
    mx = fmaxf(mx, __shfl_xor(mx, 32));
    float sum = 0.0f;
    #pragma unroll
    for (int jt = 0; jt < 4; ++jt)
      #pragma unroll
      for (int r = 0; r < 4; ++r) { s[jt][r] = __expf(s[jt][r] - mx); sum += s[jt][r]; }
    sum += __shfl_xor(sum, 16);
    sum += __shfl_xor(sum, 32);
    const float inv = 1.0f / sum;

    unsigned wpk[4][2];
    #pragma unroll
    for (int jt = 0; jt < 4; ++jt) {
      wpk[jt][0] = (unsigned)f2bu(s[jt][0] * inv) | ((unsigned)f2bu(s[jt][1] * inv) << 16);
      wpk[jt][1] = (unsigned)f2bu(s[jt][2] * inv) | ((unsigned)f2bu(s[jt][3] * inv) << 16);
    }
    #pragma unroll
    for (int ks = 0; ks < 2; ++ks) {
      union { bf16x8 v; unsigned u[4]; } pa;
      #pragma unroll
      for (int wd = 0; wd < 4; ++wd) {
        const int src = src0 + ((wd >> 1) << 4);
        unsigned v0 = (unsigned)__shfl((int)wpk[ks * 2    ][wd & 1], src);
        unsigned v1 = (unsigned)__shfl((int)wpk[ks * 2 + 1][wd & 1], src);
        pa.u[wd] = (lg & 2) ? v1 : v0;
      }
      __builtin_amdgcn_s_setprio(1);
      o[it][0] = __builtin_amdgcn_mfma_f32_16x16x32_bf16(pa.v, vb[ks][0], o[it][0], 0, 0, 0);
      o[it][1] = __builtin_amdgcn_mfma_f32_16x16x32_bf16(pa.v, vb[ks][1], o[it][1], 0, 0, 0);
      __builtin_amdgcn_s_setprio(0);
    }
  }

  #pragma unroll
  for (int it = 0; it < 4; ++it) {
    #pragma unroll
    for (int r = 0; r < 4; ++r) {
      int i = it * 16 + lg * 4 + r;
      if (i < 49) {
        size_t dst = ((size_t)w * 49 + i) * 192 + h * 32;
        attnout[dst + lr]      = __float2bfloat16(o[it][0][r]);
        attnout[dst + 16 + lr] = __float2bfloat16(o[it][1][r]);
      }
    }
  }
}

// ---------------- launcher ----------------
extern "C" void kernel_launch(void* const* d_in, const int* in_sizes, int n_in,
                              void* d_out, int out_size, void* d_ws, size_t ws_size,
                              hipStream_t stream)
{
  const float* x        = (const float*)d_in[0];
  const float* n1g      = (const float*)d_in[1];
  const float* n1b      = (const float*)d_in[2];
  const float* qkv_w    = (const float*)d_in[3];
  const float* qkv_b    = (const float*)d_in[4];
  const float* btab     = (const float*)d_in[5];
  const float* proj_w   = (const float*)d_in[6];
  const float* proj_b   = (const float*)d_in[7];
  const float* n2g      = (const float*)d_in[8];
  const float* n2b      = (const float*)d_in[9];
  const float* fc1_w    = (const float*)d_in[10];
  const float* fc1_b    = (const float*)d_in[11];
  const float* fc2_w    = (const float*)d_in[12];
  const float* fc2_b    = (const float*)d_in[13];
  float* out = (float*)d_out;

  char* ws = (char*)d_ws;
  const size_t szA = (size_t)CM * CC * 2;          // 38.5 MB: xw -> h2
  const size_t szB = (size_t)CM * CHID * 2;        // 154 MB: attnout -> hmid
  const size_t szW = (size_t)(110592 + 36864 + 147456 + 147456) * 2;
  const size_t szb2 = (size_t)98304 * 4;
  __hip_bfloat16* bufA = (__hip_bfloat16*)ws;
  __hip_bfloat16* bufB = (__hip_bfloat16*)(ws + szA);
  __hip_bfloat16* wq   = (__hip_bfloat16*)(ws + szA + szB);    // [576][192]
  __hip_bfloat16* wp   = wq + 576 * 192;                       // [192][192]
  __hip_bfloat16* w1   = wp + 192 * 192;                       // [768][192]
  __hip_bfloat16* w2   = w1 + 768 * 192;                       // [192][768]
  float* bias2         = (float*)(w2 + 192 * 768);             // [4][6][64][64]
  __hip_bfloat16* bufC = (__hip_bfloat16*)(ws + szA + szB + szW + szb2);  // x2 bf16

  // 1. fused LN1(+roll) + prep -> xw (bufA), wq/wp/w1/w2, bias2
  ln1_prep_kernel<<<LN1_BLOCKS + PREP_BLOCKS, 256, 0, stream>>>(
      x, n1g, n1b, bufA, qkv_w, proj_w, fc1_w, fc2_w, btab, wq, wp, w1, w2, bias2);
  // 2. fused qkv + attention: block = window, wave = head -> attnout (bufB)
  attn_fused_kernel<<<CB * CNW, 384, 0, stream>>>(
      (const unsigned short*)bufA, (const unsigned short*)wq, qkv_b, bias2, bufB);
  // 3. proj + reverse + roll + residual -> x2 (bf16, bufC)
  gemm_mfma<192, 192, 64, 4><<<dim3(192 / 64, CM / 128), 256, 0, stream>>>(bufB, wp, proj_b, bufC, x);
  // 4. LN2 on x2(bf16) -> h2 (bf16, bufA; xw dead)
  ln_kernel<<<CM / 4, 256, 0, stream>>>(bufC, n2g, n2b, bufA);
  // 5. fc1 + gelu -> hmid (bf16, bufB; attnout dead)
  gemm_mfma<192, CHID, 128, 2><<<dim3(CHID / 128, CM / 128), 256, 0, stream>>>(bufA, w1, fc1_b, bufB, nullptr);
  // 6. fc2: out = x2(bf16) + hmid @ w2 + b2
  gemm_mfma<CHID, 192, 64, 5><<<dim3(192 / 64, CM / 128), 256, 0, stream>>>(bufB, w2, fc2_b, out, bufC);
}

// Round 20
// 307.120 us; speedup vs baseline: 1.3001x; 1.3001x over previous
//
#include <hip/hip_runtime.h>
#include <hip/hip_bf16.h>
#include <math.h>

// ---------------- problem constants ----------------
static constexpr int CB     = 32;
static constexpr int CH     = 56;
static constexpr int CW     = 56;
static constexpr int CC     = 192;
static constexpr int CSHIFT = 3;
static constexpr int CN     = 49;
static constexpr int CNW    = 64;
static constexpr int CL     = CH * CW;            // 3136
static constexpr int CM     = CB * CNW * CN;      // 100352
static constexpr int CHID   = 768;
static constexpr int LN1_BLOCKS  = CM / 4;                    // 25088
static constexpr int PREP_TOTAL  = 110592 + 36864 + 147456 + 147456 + 98304;
static constexpr int PREP_BLOCKS = (PREP_TOTAL + 255) / 256;  // 2112

typedef __attribute__((ext_vector_type(8))) __bf16 bf16x8;
typedef __attribute__((ext_vector_type(4))) float  f32x4;

__device__ __forceinline__ float bfu2f(unsigned short u) {
  union { unsigned i; float f; } c; c.i = (unsigned)u << 16; return c.f;
}
__device__ __forceinline__ unsigned short f2bu(float f) {
  __hip_bfloat16 b = __float2bfloat16(f);
  return *(unsigned short*)&b;
}
// sigmoid-form GELU: x*sigmoid(1.702x), ~5 VALU instrs
__device__ __forceinline__ float gelu_fast(float v) {
  float e = __expf(-1.702f * v);
  return __fdividef(v, 1.0f + e);
}

#define GLOAD16(g, l) __builtin_amdgcn_global_load_lds( \
    (__attribute__((address_space(1))) void*)(g),       \
    (__attribute__((address_space(3))) void*)(l), 16, 0, 0)

// ---------------- fused LN1(+roll+window) AND one-shot prep (weights + bias2) ----------------
// Blocks [0, LN1_BLOCKS) do LN1; blocks beyond do the prep work. Prep outputs are first
// consumed by the NEXT dispatch (qkv/attn), so same-kernel ordering is irrelevant.
__global__ __launch_bounds__(256)
void ln1_prep_kernel(const float* __restrict__ xin, const float* __restrict__ gamma,
                     const float* __restrict__ beta, __hip_bfloat16* __restrict__ out,
                     const float* __restrict__ qkv_w, const float* __restrict__ proj_w,
                     const float* __restrict__ fc1_w, const float* __restrict__ fc2_w,
                     const float* __restrict__ btab,
                     __hip_bfloat16* __restrict__ wq, __hip_bfloat16* __restrict__ wp,
                     __hip_bfloat16* __restrict__ w1, __hip_bfloat16* __restrict__ w2,
                     float* __restrict__ bias2)
{
  if (blockIdx.x < LN1_BLOCKS) {
    const int wid = threadIdx.x >> 6, lane = threadIdx.x & 63;
    const int m = blockIdx.x * 4 + wid;
    int b   = m / (CNW * CN);
    int rem = m - b * (CNW * CN);
    int nw  = rem / CN, t = rem - nw * CN;
    int wr = nw >> 3, wc = nw & 7;
    int ti = t / 7, tj = t - ti * 7;
    int sr = wr * 7 + ti + CSHIFT; if (sr >= CH) sr -= CH;
    int sc = wc * 7 + tj + CSHIFT; if (sc >= CW) sc -= CW;
    size_t src = ((size_t)b * CL + (size_t)sr * CW + sc) * CC;
    float v0 = xin[src + lane], v1 = xin[src + lane + 64], v2 = xin[src + lane + 128];
    float s  = v0 + v1 + v2;
    float sq = v0 * v0 + v1 * v1 + v2 * v2;
    #pragma unroll
    for (int off = 32; off; off >>= 1) { s += __shfl_xor(s, off); sq += __shfl_xor(sq, off); }
    const float mu  = s * (1.0f / CC);
    const float inv = rsqrtf(sq * (1.0f / CC) - mu * mu + 1e-5f);
    const size_t dst = (size_t)m * CC;
    out[dst + lane      ] = __float2bfloat16((v0 - mu) * inv * gamma[lane      ] + beta[lane      ]);
    out[dst + lane + 64 ] = __float2bfloat16((v1 - mu) * inv * gamma[lane + 64 ] + beta[lane + 64 ]);
    out[dst + lane + 128] = __float2bfloat16((v2 - mu) * inv * gamma[lane + 128] + beta[lane + 128]);
    return;
  }

  int idx = (blockIdx.x - LN1_BLOCKS) * 256 + threadIdx.x;
  if (idx < 110592) {                       // wq: [192][576] -> [576][192]
    int k = idx / 576, n = idx - k * 576;
    wq[n * 192 + k] = __float2bfloat16(qkv_w[idx]);
    return;
  }
  idx -= 110592;
  if (idx < 36864) {                        // wp: [192][192]
    int k = idx / 192, n = idx - k * 192;
    wp[n * 192 + k] = __float2bfloat16(proj_w[idx]);
    return;
  }
  idx -= 36864;
  if (idx < 147456) {                       // w1: [192][768] -> [768][192]
    int k = idx / 768, n = idx - k * 768;
    w1[n * 192 + k] = __float2bfloat16(fc1_w[idx]);
    return;
  }
  idx -= 147456;
  if (idx < 147456) {                       // w2: [768][192] -> [192][768]
    int k = idx / 192, n = idx - k * 192;
    w2[n * 768 + k] = __float2bfloat16(fc2_w[idx]);
    return;
  }
  idx -= 147456;
  if (idx < 98304) {                        // bias2: [4][6][64][64]
    int j = idx & 63, i = (idx >> 6) & 63;
    int rest = idx >> 12;
    int h = rest % 6, wt = rest / 6;
    float val;
    if (i >= 49 || j >= 49) {
      val = -INFINITY;
    } else {
      int ti = i / 7, ci = i - ti * 7;
      int tj = j / 7, cj = j - tj * 7;
      val = btab[((ti - tj + 6) * 13 + (ci - cj + 6)) * 6 + h];
      int hri = (wt & 2) ? ((ti < 4) ? 1 : 2) : 0;
      int hci = (wt & 1) ? ((ci < 4) ? 1 : 2) : 0;
      int hrj = (wt & 2) ? ((tj < 4) ? 1 : 2) : 0;
      int hcj = (wt & 1) ? ((cj < 4) ? 1 : 2) : 0;
      if (hri * 3 + hci != hrj * 3 + hcj) val -= 100.0f;
    }
    bias2[idx] = val;
  }
}

// ---------------- LN2 (bf16 in/out, no roll) ----------------
__global__ __launch_bounds__(256)
void ln_kernel(const __hip_bfloat16* __restrict__ xin, const float* __restrict__ gamma,
               const float* __restrict__ beta, __hip_bfloat16* __restrict__ out)
{
  const int wid = threadIdx.x >> 6, lane = threadIdx.x & 63;
  const int m = blockIdx.x * 4 + wid;
  const size_t src = (size_t)m * CC;
  const unsigned short* xb = (const unsigned short*)xin;
  float v0 = bfu2f(xb[src + lane      ]);
  float v1 = bfu2f(xb[src + lane + 64 ]);
  float v2 = bfu2f(xb[src + lane + 128]);
  float s  = v0 + v1 + v2;
  float sq = v0 * v0 + v1 * v1 + v2 * v2;
  #pragma unroll
  for (int off = 32; off; off >>= 1) { s += __shfl_xor(s, off); sq += __shfl_xor(sq, off); }
  const float mu  = s * (1.0f / CC);
  const float inv = rsqrtf(sq * (1.0f / CC) - mu * mu + 1e-5f);
  out[src + lane      ] = __float2bfloat16((v0 - mu) * inv * gamma[lane      ] + beta[lane      ]);
  out[src + lane + 64 ] = __float2bfloat16((v1 - mu) * inv * gamma[lane + 64 ] + beta[lane + 64 ]);
  out[src + lane + 128] = __float2bfloat16((v2 - mu) * inv * gamma[lane + 128] + beta[lane + 128]);
}

// ---------------- MFMA bf16 GEMM: BM=128, BN in {64,96,128}, BK=64, 4 waves (2x2) ----------------
// Round-11 skeleton (single buffer, 2 barriers/K-step, verified 8-slot swizzle).
// MODE 0: Out(bf16)=A@W+bias (qkv) | 2: gelu bf16 (fc1)
// MODE 4: scatter bf16 resid (proj) | 5: bf16-resid f32 out (fc2)
template<int K, int N, int BN, int MODE>
__global__ __launch_bounds__(256)
void gemm_mfma(const __hip_bfloat16* __restrict__ Ain, const __hip_bfloat16* __restrict__ Wt,
               const float* __restrict__ bias, void* __restrict__ Outv,
               const void* __restrict__ residv)
{
  constexpr int NT = BN / 32;
  __shared__ short As[128 * 64];
  __shared__ short Bs[BN * 64];

  const int tid  = threadIdx.x;
  const int lane = tid & 63, wid = tid >> 6;

  const int nbx = N / BN;
  const int nwg = nbx * gridDim.y;
  const int wg  = blockIdx.y * nbx + blockIdx.x;
  const int swz = (wg & 7) * (nwg >> 3) + (wg >> 3);
  const int row0 = (swz / nbx) * 128, col0 = (swz % nbx) * BN;

  const int wm = wid >> 1, wn = wid & 1;
  const int lr = lane & 15, lg = lane >> 4;

  const short* A  = (const short*)Ain;
  const short* W  = (const short*)Wt;

  f32x4 acc[4][NT] = {};

  #pragma unroll
  for (int kk = 0; kk < K; kk += 64) {
    #pragma unroll
    for (int it = 0; it < 4; ++it) {
      int c = it * 256 + tid;
      int row = c >> 3, slot = c & 7;
      int kg = (slot ^ (row & 7)) * 8;
      GLOAD16(A + (size_t)(row0 + row) * K + kk + kg, As + c * 8);
    }
    #pragma unroll
    for (int it = 0; it < BN / 32; ++it) {
      int c = it * 256 + tid;
      int row = c >> 3, slot = c & 7;
      int kg = (slot ^ (row & 7)) * 8;
      GLOAD16(W + (size_t)(col0 + row) * K + kk + kg, Bs + c * 8);
    }
    __syncthreads();

    #pragma unroll
    for (int kh = 0; kh < 2; ++kh) {
      const int sb = kh * 4 + lg;
      bf16x8 bfr[NT];
      #pragma unroll
      for (int nt = 0; nt < NT; ++nt) {
        int br = wn * (BN / 2) + nt * 16 + lr;
        bfr[nt] = *(const bf16x8*)(Bs + br * 64 + (sb ^ (br & 7)) * 8);
      }
      #pragma unroll
      for (int m = 0; m < 4; ++m) {
        int ar = wm * 64 + m * 16 + lr;
        bf16x8 afr = *(const bf16x8*)(As + ar * 64 + (sb ^ (ar & 7)) * 8);
        #pragma unroll
        for (int nt = 0; nt < NT; ++nt)
          acc[m][nt] = __builtin_amdgcn_mfma_f32_16x16x32_bf16(afr, bfr[nt], acc[m][nt], 0, 0, 0);
      }
    }
    __syncthreads();
  }

  const int colA = col0 + wn * (BN / 2) + lr;
  float bv[NT];
  #pragma unroll
  for (int nt = 0; nt < NT; ++nt) bv[nt] = bias[colA + nt * 16];

  #pragma unroll
  for (int m = 0; m < 4; ++m) {
    #pragma unroll
    for (int r = 0; r < 4; ++r) {
      const int mrow = row0 + wm * 64 + m * 16 + lg * 4 + r;
      if (MODE == 0) {
        __hip_bfloat16* O = (__hip_bfloat16*)Outv;
        const size_t rr = (size_t)mrow * N + colA;
        #pragma unroll
        for (int nt = 0; nt < NT; ++nt)
          O[rr + nt * 16] = __float2bfloat16(acc[m][nt][r] + bv[nt]);
      } else if (MODE == 4) {
        int b = mrow / (CNW * CN);
        int rem = mrow - b * (CNW * CN);
        int nw = rem / CN, t = rem - nw * CN;
        int wr = nw >> 3, wc = nw & 7;
        int ti = t / 7, tj = t - ti * 7;
        int dr = wr * 7 + ti + CSHIFT; if (dr >= CH) dr -= CH;
        int dc = wc * 7 + tj + CSHIFT; if (dc >= CW) dc -= CW;
        const size_t dst = ((size_t)b * CL + (size_t)dr * CW + dc) * CC + colA;
        const float* resid = (const float*)residv;
        __hip_bfloat16* O = (__hip_bfloat16*)Outv;
        #pragma unroll
        for (int nt = 0; nt < NT; ++nt)
          O[dst + nt * 16] = __float2bfloat16(resid[dst + nt * 16] + acc[m][nt][r] + bv[nt]);
      } else if (MODE == 2) {
        __hip_bfloat16* O = (__hip_bfloat16*)Outv;
        const size_t rr = (size_t)mrow * N + colA;
        #pragma unroll
        for (int nt = 0; nt < NT; ++nt)
          O[rr + nt * 16] = __float2bfloat16(gelu_fast(acc[m][nt][r] + bv[nt]));
      } else {
        float* O = (float*)Outv;
        const unsigned short* resid = (const unsigned short*)residv;
        const size_t rr = (size_t)mrow * N + colA;
        #pragma unroll
        for (int nt = 0; nt < NT; ++nt)
          O[rr + nt * 16] = bfu2f(resid[rr + nt * 16]) + acc[m][nt][r] + bv[nt];
      }
    }
  }
}

// ---------------- MFMA windowed attention: 4 (window,head) pairs per 256-thread block ----------------
__global__ __launch_bounds__(256)
void attn_mfma_kernel(const __hip_bfloat16* __restrict__ qkv,
                      const float* __restrict__ bias2,
                      __hip_bfloat16* __restrict__ attnout)
{
  __shared__ unsigned short VT[4][32 * 72];   // per-wave V^T [d][tok], stride 72

  const int wid = threadIdx.x >> 6;
  const int gid = blockIdx.x * 4 + wid;
  const int w = gid / 6, h = gid - (gid / 6) * 6;
  const int lane = threadIdx.x & 63;
  const int lr = lane & 15, lg = lane >> 4;
  const int nw = w & 63;
  const int wt = (((nw >> 3) == 7) ? 2 : 0) + (((nw & 7) == 7) ? 1 : 0);
  const unsigned short* Q = (const unsigned short*)qkv;
  const size_t rowbase = (size_t)w * 49 * 576;
  const float scale = 0.17677669529663687f;
  unsigned short* vt = VT[wid];

  for (int e = lane; e < 196; e += 64) {
    int t = e % 49, c = e / 49;
    uint4 v = *(const uint4*)(Q + rowbase + (size_t)t * 576 + 384 + h * 32 + c * 8);
    unsigned va[4] = {v.x, v.y, v.z, v.w};
    #pragma unroll
    for (int q = 0; q < 4; ++q) {
      vt[(c * 8 + q * 2    ) * 72 + t] = (unsigned short)(va[q] & 0xffff);
      vt[(c * 8 + q * 2 + 1) * 72 + t] = (unsigned short)(va[q] >> 16);
    }
  }
  for (int e = lane; e < 32 * 15; e += 64) {
    int d = e / 15, t = 49 + e - (e / 15) * 15;
    vt[d * 72 + t] = 0;
  }

  bf16x8 qf[4], kf[4];
  #pragma unroll
  for (int it = 0; it < 4; ++it) {
    int tok = it * 16 + lr; if (tok > 48) tok = 48;
    qf[it] = *(const bf16x8*)(Q + rowbase + (size_t)tok * 576 + h * 32 + lg * 8);
  }
  #pragma unroll
  for (int jt = 0; jt < 4; ++jt) {
    int tok = jt * 16 + lr; if (tok > 48) tok = 48;
    kf[jt] = *(const bf16x8*)(Q + rowbase + (size_t)tok * 576 + 192 + h * 32 + lg * 8);
  }

  f32x4 acc[4][4] = {};
  __builtin_amdgcn_s_setprio(1);
  #pragma unroll
  for (int jt = 0; jt < 4; ++jt)
    #pragma unroll
    for (int it = 0; it < 4; ++it)
      acc[jt][it] = __builtin_amdgcn_mfma_f32_16x16x32_bf16(kf[jt], qf[it], acc[jt][it], 0, 0, 0);
  __builtin_amdgcn_s_setprio(0);

  __syncthreads();   // V^T staged (all 4 waves)

  bf16x8 vb[2][2];
  #pragma unroll
  for (int ks = 0; ks < 2; ++ks)
    #pragma unroll
    for (int nt = 0; nt < 2; ++nt)
      vb[ks][nt] = *(const bf16x8*)&vt[(nt * 16 + lr) * 72 + ks * 32 + lg * 8];

  const float* brow = bias2 + ((size_t)(wt * 6 + h) * 64) * 64;
  const int src0 = lr + ((lg & 1) << 5);
  f32x4 o[4][2] = {};

  #pragma unroll
  for (int it = 0; it < 4; ++it) {
    const int i = it * 16 + lr;
    float s[4][4];
    #pragma unroll
    for (int jt = 0; jt < 4; ++jt) {
      float4 bv = *(const float4*)(brow + (size_t)i * 64 + jt * 16 + lg * 4);
      s[jt][0] = fmaf(acc[jt][it][0], scale, bv.x);
      s[jt][1] = fmaf(acc[jt][it][1], scale, bv.y);
      s[jt][2] = fmaf(acc[jt][it][2], scale, bv.z);
      s[jt][3] = fmaf(acc[jt][it][3], scale, bv.w);
    }
    float mx = s[0][0];
    #pragma unroll
    for (int jt = 0; jt < 4; ++jt)
      #pragma unroll
      for (int r = 0; r < 4; ++r) mx = fmaxf(mx, s[jt][r]);
    mx = fmaxf(mx, __shfl_xor(mx, 16));
    mx = fmaxf(mx, __shfl_xor(mx, 32));
    float sum = 0.0f;
    #pragma unroll
    for (int jt = 0; jt < 4; ++jt)
      #pragma unroll
      for (int r = 0; r < 4; ++r) { s[jt][r] = __expf(s[jt][r] - mx); sum += s[jt][r]; }
    sum += __shfl_xor(sum, 16);
    sum += __shfl_xor(sum, 32);
    const float inv = 1.0f / sum;

    unsigned wpk[4][2];
    #pragma unroll
    for (int jt = 0; jt < 4; ++jt) {
      wpk[jt][0] = (unsigned)f2bu(s[jt][0] * inv) | ((unsigned)f2bu(s[jt][1] * inv) << 16);
      wpk[jt][1] = (unsigned)f2bu(s[jt][2] * inv) | ((unsigned)f2bu(s[jt][3] * inv) << 16);
    }
    #pragma unroll
    for (int ks = 0; ks < 2; ++ks) {
      union { bf16x8 v; unsigned u[4]; } pa;
      #pragma unroll
      for (int wd = 0; wd < 4; ++wd) {
        const int src = src0 + ((wd >> 1) << 4);
        unsigned v0 = (unsigned)__shfl((int)wpk[ks * 2    ][wd & 1], src);
        unsigned v1 = (unsigned)__shfl((int)wpk[ks * 2 + 1][wd & 1], src);
        pa.u[wd] = (lg & 2) ? v1 : v0;
      }
      __builtin_amdgcn_s_setprio(1);
      o[it][0] = __builtin_amdgcn_mfma_f32_16x16x32_bf16(pa.v, vb[ks][0], o[it][0], 0, 0, 0);
      o[it][1] = __builtin_amdgcn_mfma_f32_16x16x32_bf16(pa.v, vb[ks][1], o[it][1], 0, 0, 0);
      __builtin_amdgcn_s_setprio(0);
    }
  }

  #pragma unroll
  for (int it = 0; it < 4; ++it) {
    #pragma unroll
    for (int r = 0; r < 4; ++r) {
      int i = it * 16 + lg * 4 + r;
      if (i < 49) {
        size_t dst = ((size_t)w * 49 + i) * 192 + h * 32;
        attnout[dst + lr]      = __float2bfloat16(o[it][0][r]);
        attnout[dst + 16 + lr] = __float2bfloat16(o[it][1][r]);
      }
    }
  }
}

// ---------------- launcher ----------------
extern "C" void kernel_launch(void* const* d_in, const int* in_sizes, int n_in,
                              void* d_out, int out_size, void* d_ws, size_t ws_size,
                              hipStream_t stream)
{
  const float* x        = (const float*)d_in[0];
  const float* n1g      = (const float*)d_in[1];
  const float* n1b      = (const float*)d_in[2];
  const float* qkv_w    = (const float*)d_in[3];
  const float* qkv_b    = (const float*)d_in[4];
  const float* btab     = (const float*)d_in[5];
  const float* proj_w   = (const float*)d_in[6];
  const float* proj_b   = (const float*)d_in[7];
  const float* n2g      = (const float*)d_in[8];
  const float* n2b      = (const float*)d_in[9];
  const float* fc1_w    = (const float*)d_in[10];
  const float* fc1_b    = (const float*)d_in[11];
  const float* fc2_w    = (const float*)d_in[12];
  const float* fc2_b    = (const float*)d_in[13];
  float* out = (float*)d_out;

  char* ws = (char*)d_ws;
  const size_t szA = (size_t)CM * CC * 2;          // 38.5 MB: xw -> attnout -> h2
  const size_t szB = (size_t)CM * CHID * 2;        // 154 MB: qkv(576) -> hmid(768)
  const size_t szW = (size_t)(110592 + 36864 + 147456 + 147456) * 2;
  const size_t szb2 = (size_t)98304 * 4;
  __hip_bfloat16* bufA = (__hip_bfloat16*)ws;
  __hip_bfloat16* bufB = (__hip_bfloat16*)(ws + szA);
  __hip_bfloat16* wq   = (__hip_bfloat16*)(ws + szA + szB);    // [576][192]
  __hip_bfloat16* wp   = wq + 576 * 192;                       // [192][192]
  __hip_bfloat16* w1   = wp + 192 * 192;                       // [768][192]
  __hip_bfloat16* w2   = w1 + 768 * 192;                       // [192][768]
  float* bias2         = (float*)(w2 + 192 * 768);             // [4][6][64][64]
  __hip_bfloat16* bufC = (__hip_bfloat16*)(ws + szA + szB + szW + szb2);  // x2 bf16 trunk

  // 1. fused LN1(+roll) + prep (weights/bias2) -> xw, wq/wp/w1/w2, bias2
  ln1_prep_kernel<<<LN1_BLOCKS + PREP_BLOCKS, 256, 0, stream>>>(
      x, n1g, n1b, bufA, qkv_w, proj_w, fc1_w, fc2_w, btab, wq, wp, w1, w2, bias2);
  // 2. qkv = xw @ wq + qkv_b -> bf16 [CM,576]  (BN=96)
  gemm_mfma<192, 576, 96, 0><<<dim3(576 / 96, CM / 128), 256, 0, stream>>>(bufA, wq, qkv_b, bufB, nullptr);
  // 3. MFMA windowed attention, 4 (w,h)/block -> attnout (bf16, reuses bufA)
  attn_mfma_kernel<<<2048 * 6 / 4, 256, 0, stream>>>(bufB, bias2, bufA);
  // 4. proj + reverse + roll + residual -> x2 (bf16, bufC)
  gemm_mfma<192, 192, 64, 4><<<dim3(192 / 64, CM / 128), 256, 0, stream>>>(bufA, wp, proj_b, bufC, x);
  // 5. LN2 on x2(bf16) -> h2 (bf16, bufA)
  ln_kernel<<<CM / 4, 256, 0, stream>>>(bufC, n2g, n2b, bufA);
  // 6. fc1 + gelu -> hmid (bf16, bufB)  (BN=128)
  gemm_mfma<192, CHID, 128, 2><<<dim3(CHID / 128, CM / 128), 256, 0, stream>>>(bufA, w1, fc1_b, bufB, nullptr);
  // 7. fc2: out = x2(bf16) + hmid @ w2 + b2  (BM=128, BN=64 — round-16 optimum)
  gemm_mfma<CHID, 192, 64, 5><<<dim3(192 / 64, CM / 128), 256, 0, stream>>>(bufB, w2, fc2_b, out, bufC);
}